// Round 12
// baseline (1172.107 us; speedup 1.0000x reference)
//
#include <hip/hip_runtime.h>
#include <hip/hip_bf16.h>

// N=65536 points, H=256, 4 hidden layers, ReLU MLP -> (psi,p).
// ReLU => piecewise linear => Hessians vanish; f = p_x, g = p_y (RHO=1).
// Pipeline:
//   1) fp32 forward replicating np/BLAS arithmetic BIT-EXACTLY
//      (k-ascending single-acc fmaf chain, bias after, mask = a>0).
//      v12: v11 mapping (1024 thr = 16 waves x 16 cols, 2 pts/lane,
//      hT[128][257] LDS) but W transported via VMEM (global_load_dwordx4
//      on a wave-uniform address made opaque with a v_mov asm VGPR) --
//      K$ supply was the ~4.3 B/cyc wall pinning VALUBusy at 68%; L1
//      uniform-tx supply is ~16x that, and vmcnt decouples W waits from
//      the lgkmcnt h reads so the compiler can pipeline 4 k-steps deep.
//   2) ONE fused tangent kernel (v7): T1 init from masks+Win, 4 MFMA
//      layers with mask-gated f16 LDS roundtrip, fused finalize.
// Workspace: masks 5x2MB | Wt 512KB

#define NPTS 65536
#define HDIM 256

typedef _Float16 half8_t __attribute__((ext_vector_type(8)));
typedef _Float16 half4_t __attribute__((ext_vector_type(4)));
typedef float floatx4 __attribute__((ext_vector_type(4)));

// ---------------------------------------------------------------- fused fp32 forward (np/BLAS-exact)
// 1024 threads = 16 waves, 128 pts/block. lane -> points (p0+lane, p0+64+lane);
// wave w -> cols c0=w*16. W loads: wave-uniform address + opaque VGPR zero ->
// global_load_dwordx4 (one L1 tx per load, vmcnt-pipelined). hT[pt][k] stride
// 257 (conflict-free). Each output element is ONE sequential k-ascending fmaf
// chain from 0, bias added after (bit-exact vs np reference).
__global__ void __launch_bounds__(1024, 4) fwd_fused_kernel(
    const float* __restrict__ x, const float* __restrict__ y, const float* __restrict__ t,
    const float* __restrict__ Win, const float* __restrict__ b_in,
    const float* __restrict__ Wh, const float* __restrict__ b_h,
    const float* __restrict__ Wout, const float* __restrict__ b_out,
    unsigned char* __restrict__ masks, float* __restrict__ out) {
  constexpr int SH = 257;              // odd stride: conflict-free b32
  __shared__ float hT[128 * SH];       // [pt][k]  131584 B
  __shared__ float pscr[16][132];      // wave partials for p (8448 B)

  const int tid = threadIdx.x;
  const int lane = tid & 63;
  const int w = __builtin_amdgcn_readfirstlane(tid >> 6);       // wave id 0..15
  const int c0 = w * 16;                                        // 16-col group
  const int p0 = blockIdx.x * 128;
  const int pA = p0 + lane;            // point A
  const int pB = p0 + 64 + lane;       // point B

  // opaque VGPR zero: forces W addresses into VMEM (global_load) instead of
  // the scalar K$ path; value is 0 so addresses (and results) are unchanged.
  int vzero;
  asm("v_mov_b32 %0, 0" : "=v"(vzero));

  // ---- layer 1: dot = z @ Win (k ascending: x,y,t), then + b_in  [bit-exact]
  {
    float xa = x[pA], ya = y[pA], ta = t[pA];
    float xb = x[pB], yb = y[pB], tb = t[pB];
    unsigned ma = 0, mb = 0;
#pragma unroll
    for (int e = 0; e < 16; ++e) {
      int c = c0 + e;
      float w0 = Win[c], w1 = Win[256 + c], w2 = Win[512 + c], bb = b_in[c];
      float da = fmaf(xa, w0, 0.f);
      da = fmaf(ya, w1, da);
      da = fmaf(ta, w2, da);
      float aa = da + bb;
      bool posa = aa > 0.f;
      hT[lane * SH + c] = posa ? aa : 0.f;
      ma |= (posa ? 1u : 0u) << e;
      float db = fmaf(xb, w0, 0.f);
      db = fmaf(yb, w1, db);
      db = fmaf(tb, w2, db);
      float ab = db + bb;
      bool posb = ab > 0.f;
      hT[(64 + lane) * SH + c] = posb ? ab : 0.f;
      mb |= (posb ? 1u : 0u) << e;
    }
    *(unsigned short*)(masks + (size_t)pA * 32 + w * 2) = (unsigned short)ma;
    *(unsigned short*)(masks + (size_t)pB * 32 + w * 2) = (unsigned short)mb;
  }
  __syncthreads();

  // ---- hidden layers: single fp32 accumulator per element, k ascending, fmaf
  for (int l = 0; l < 4; ++l) {
    const float* Wl = Wh + (size_t)l * 65536 + c0 + vzero;  // VGPR-tainted base
    float accA[16] = {};
    float accB[16] = {};
#pragma unroll 4
    for (int k = 0; k < 256; ++k) {
      float hA = hT[lane * SH + k];          // per-lane LDS (lgkmcnt)
      float hB = hT[(64 + lane) * SH + k];
      const float4* wr4 = (const float4*)(Wl + (size_t)k * 256);  // VMEM (vmcnt)
      float4 wq0 = wr4[0], wq1 = wr4[1], wq2 = wr4[2], wq3 = wr4[3];
      float wv[16] = {wq0.x, wq0.y, wq0.z, wq0.w, wq1.x, wq1.y, wq1.z, wq1.w,
                      wq2.x, wq2.y, wq2.z, wq2.w, wq3.x, wq3.y, wq3.z, wq3.w};
#pragma unroll
      for (int e = 0; e < 16; ++e) {
        accA[e] = fmaf(hA, wv[e], accA[e]);
        accB[e] = fmaf(hB, wv[e], accB[e]);
      }
    }
    __syncthreads();                   // all hT reads done before overwrite
    unsigned ma = 0, mb = 0;
    float hnA[16], hnB[16];
#pragma unroll
    for (int e = 0; e < 16; ++e) {
      float bb = b_h[l * 256 + c0 + e];
      float aa = accA[e] + bb;
      bool posa = aa > 0.f;
      hnA[e] = posa ? aa : 0.f;
      ma |= (posa ? 1u : 0u) << e;
      float ab = accB[e] + bb;
      bool posb = ab > 0.f;
      hnB[e] = posb ? ab : 0.f;
      mb |= (posb ? 1u : 0u) << e;
    }
    *(unsigned short*)(masks + ((size_t)(l + 1) * NPTS + pA) * 32 + w * 2) =
        (unsigned short)ma;
    *(unsigned short*)(masks + ((size_t)(l + 1) * NPTS + pB) * 32 + w * 2) =
        (unsigned short)mb;
#pragma unroll
    for (int e = 0; e < 16; ++e) {
      hT[lane * SH + c0 + e] = hnA[e];
      hT[(64 + lane) * SH + c0 + e] = hnB[e];
    }
    __syncthreads();
  }

  // ---- p = h5 . Wout[:,1] + b_out[1]  (value output; order-insensitive at
  //      bf16 comparison granularity)
  {
    float sA = 0.f, sB = 0.f;
#pragma unroll
    for (int e = 0; e < 16; ++e) {
      float wv = Wout[2 * (c0 + e) + 1];
      sA = fmaf(hT[lane * SH + c0 + e], wv, sA);
      sB = fmaf(hT[(64 + lane) * SH + c0 + e], wv, sB);
    }
    pscr[w][lane] = sA;
    pscr[w][64 + lane] = sB;
  }
  __syncthreads();
  if (tid < 128) {
    float s2 = 0.f;
#pragma unroll
    for (int g = 0; g < 16; ++g) s2 += pscr[g][tid];
    out[2 * NPTS + p0 + tid] = s2 + b_out[1];
  }
}

// ---------------------------------------------------------------- prep: Wh fp32 [l][k][n] -> f16 [l][n][k]
__global__ void __launch_bounds__(256) prep_weights_kernel(
    const float* __restrict__ Wh, _Float16* __restrict__ Wt) {
  int i = blockIdx.x * 256 + threadIdx.x;   // 0..262143
  int l = i >> 16;
  int rem = i & 65535;
  int k = rem >> 8, n = rem & 255;
  Wt[(size_t)(l << 16) + n * 256 + k] = (_Float16)Wh[i];
}

// ---------------------------------------------------------------- fused tangent chain (init + 4 layers + finalize)
// Block: 256 thr = 4 waves. 32 points -> 64 rows (0..31 x-tangent, 32..63 y).
// Tile M=64 x N=256; wave wn owns 64 rows x 64 cols (acc 4x4 16x16 tiles).
// T lives in Apan (f16) across layers; W streamed in 64-k chunks to Bpan.
// mfma_f32_16x16x32_f16: A[m=lane&15][k=quad*8+j], B[k=quad*8+j][n=lane&15],
//                        D[row=quad*4+reg][col=lane&15]  (verified layouts)
__global__ void __launch_bounds__(256, 2) tangent_fused_kernel(
    const float* __restrict__ Win,
    const _Float16* __restrict__ Wt,          // [l][n][k] (pre-transposed)
    const unsigned int* __restrict__ maskDw,  // [5][NPTS][8] dwords
    const float* __restrict__ Wout, float* __restrict__ out) {
  constexpr int SA = 264;   // A row stride (halves): 256 + 8 pad
  constexpr int SB = 72;    // B row stride (halves): 64 + 8 pad
  __shared__ alignas(16) _Float16 Apan[64 * SA];    // 33792 B
  __shared__ alignas(16) _Float16 Bpan[256 * SB];   // 36864 B
  __shared__ unsigned int smask[5 * 256];           // 5120 B

  const int tid = threadIdx.x;
  const int lane = tid & 63;
  const int wn = tid >> 6;          // wave = 64-col group
  const int l15 = lane & 15, quad = lane >> 4;
  const int p0 = blockIdx.x * 32;   // 32 points per block

  // ---- stage all 5 mask layers (32 pts x 8 dw each)
#pragma unroll
  for (int i = 0; i < 5; ++i)
    smask[i * 256 + tid] = maskDw[(size_t)i * NPTS * 8 + (size_t)p0 * 8 + tid];
  __syncthreads();

  // ---- init T1 into Apan: row<32 -> x-tangent (Win row 0), row>=32 -> y (row 1)
#pragma unroll
  for (int i = 0; i < 8; ++i) {
    int g = tid + 256 * i;          // 0..2047 col-groups of 8
    int row = g >> 5, cg = g & 31;
    int c0 = cg * 8, pt = row & 31, tg = row >> 5;
    unsigned dw = smask[pt * 8 + (c0 >> 5)];
    half8_t v;
#pragma unroll
    for (int e = 0; e < 8; ++e) {
      bool m = (dw >> ((cg & 3) * 8 + e)) & 1;
      v[e] = m ? (_Float16)Win[tg * 256 + c0 + e] : (_Float16)0.f;
    }
    *(half8_t*)&Apan[row * SA + c0] = v;
  }

  // ---- 4 layers: acc = A @ W_l, gate by mask[l+1], back into Apan as f16
  for (int l = 0; l < 4; ++l) {
    const _Float16* Wl = Wt + (size_t)l * 65536;
    floatx4 acc[4][4] = {};   // [mi][nj]
    for (int kp = 0; kp < 4; ++kp) {
      __syncthreads();        // Bpan free (and Apan init/writes visible)
      // stage B chunk: 256 n-rows x 64 k halves
#pragma unroll
      for (int i = 0; i < 8; ++i) {
        int g = tid + 256 * i;      // 0..2047 half8 segs
        int row = g >> 3, seg = g & 7;
        *(half8_t*)&Bpan[row * SB + seg * 8] =
            *(const half8_t*)(Wl + (size_t)row * 256 + kp * 64 + seg * 8);
      }
      __syncthreads();
#pragma unroll
      for (int ks = 0; ks < 2; ++ks) {
        half8_t af[4], bf[4];
#pragma unroll
        for (int mi = 0; mi < 4; ++mi)
          af[mi] = *(const half8_t*)&Apan[(mi * 16 + l15) * SA + kp * 64 + ks * 32 + quad * 8];
#pragma unroll
        for (int nj = 0; nj < 4; ++nj)
          bf[nj] = *(const half8_t*)&Bpan[(wn * 64 + nj * 16 + l15) * SB + ks * 32 + quad * 8];
#pragma unroll
        for (int mi = 0; mi < 4; ++mi)
#pragma unroll
          for (int nj = 0; nj < 4; ++nj)
            acc[mi][nj] = __builtin_amdgcn_mfma_f32_16x16x32_f16(af[mi], bf[nj], acc[mi][nj], 0, 0, 0);
      }
    }
    __syncthreads();          // all Apan reads of this layer done
    // gated write-back (C layout -> A storage), f16
    const unsigned int* ml = &smask[(l + 1) * 256];
#pragma unroll
    for (int mi = 0; mi < 4; ++mi) {
#pragma unroll
      for (int r = 0; r < 4; ++r) {
        int row = mi * 16 + quad * 4 + r;
        int pt = row & 31;
#pragma unroll
        for (int nj = 0; nj < 4; ++nj) {
          int C = wn * 64 + nj * 16 + l15;
          bool m = (ml[pt * 8 + (C >> 5)] >> (C & 31)) & 1;
          Apan[row * SA + C] = m ? (_Float16)acc[mi][nj][r] : (_Float16)0.f;
        }
      }
    }
    __syncthreads();
  }

  // ---- finalize from Apan (= T5 gated): per row, dots with Wout cols
  float4 wA = *(const float4*)(Wout + lane * 8);      // (W[c][0],W[c][1],W[c+1][0],W[c+1][1])
  float4 wB = *(const float4*)(Wout + lane * 8 + 4);
  float w0[4] = {wA.x, wA.z, wB.x, wB.z};  // Wout[:,0] for cols lane*4..+3
  float w1[4] = {wA.y, wA.w, wB.y, wB.w};  // Wout[:,1]
#pragma unroll
  for (int i = 0; i < 16; ++i) {
    int row = wn * 16 + i;
    half4_t hv = *(const half4_t*)&Apan[row * SA + lane * 4];
    float s0 = 0.f, s1 = 0.f;
#pragma unroll
    for (int e = 0; e < 4; ++e) {
      float fv = (float)hv[e];
      s0 = fmaf(fv, w0[e], s0);
      s1 = fmaf(fv, w1[e], s1);
    }
#pragma unroll
    for (int off = 1; off < 64; off <<= 1) {
      s0 += __shfl_xor(s0, off);
      s1 += __shfl_xor(s1, off);
    }
    if (lane == 0) {
      int pt = p0 + (row & 31);
      if (row < 32) {                 // x-tangent: v = -psi_x, f = p_x
        out[NPTS + pt] = -s0;
        out[3 * NPTS + pt] = s1;
      } else {                        // y-tangent: u = psi_y, g = p_y
        out[pt] = s0;
        out[4 * NPTS + pt] = s1;
      }
    }
  }
}

// ---------------------------------------------------------------- launch
extern "C" void kernel_launch(void* const* d_in, const int* in_sizes, int n_in,
                              void* d_out, int out_size, void* d_ws, size_t ws_size,
                              hipStream_t stream) {
  const float* x = (const float*)d_in[0];
  const float* y = (const float*)d_in[1];
  const float* t = (const float*)d_in[2];
  const float* Win = (const float*)d_in[3];
  const float* b_in = (const float*)d_in[4];
  const float* Wh = (const float*)d_in[5];
  const float* b_h = (const float*)d_in[6];
  const float* Wout = (const float*)d_in[7];
  const float* b_out = (const float*)d_in[8];
  float* out = (float*)d_out;

  char* ws = (char*)d_ws;
  constexpr size_t MASK_SZ = (size_t)NPTS * 32;       // 2 MB per layer
  unsigned char* masks = (unsigned char*)ws;
  _Float16* Wt = (_Float16*)(ws + 5 * MASK_SZ);

  // weight transpose/cast first (independent of fwd)
  prep_weights_kernel<<<1024, 256, 0, stream>>>(Wh, Wt);

  // fp32 np-exact forward: masks L0..L4 + p
  fwd_fused_kernel<<<NPTS / 128, 1024, 0, stream>>>(
      x, y, t, Win, b_in, Wh, b_h, Wout, b_out, masks, out);

  // fused tangent chain: init + 4 MFMA layers + finalize (u,v,f,g)
  tangent_fused_kernel<<<NPTS / 32, 256, 0, stream>>>(
      Win, Wt, (const unsigned int*)masks, Wout, out);
}

// Round 13
// 639.578 us; speedup vs baseline: 1.8326x; 1.8326x over previous
//
#include <hip/hip_runtime.h>
#include <hip/hip_bf16.h>

// N=65536 points, H=256, 4 hidden layers, ReLU MLP -> (psi,p).
// ReLU => piecewise linear => Hessians vanish; f = p_x, g = p_y (RHO=1).
// Pipeline:
//   1) fp32 forward replicating np/BLAS arithmetic BIT-EXACTLY (v11 kernel,
//      UNMODIFIED: 1024 thr = 16 waves x 16 cols, 2 pts/lane, hT[128][257],
//      W via wave-uniform s_load; 404 us, ~83% of scalar-FMA ceiling).
//      v12's VMEM-W detour collapsed to 25% busy - reverted.
//   2) v13 fused tangent kernel: B fragments load DIRECTLY from global to
//      registers (no Bpan LDS, no staging barriers - 2 barriers/layer not 8).
//      LDS 39 KB -> 4 blocks/CU = 16 waves/CU. Same MFMA order -> outputs
//      bit-identical to v7/v11 tangent path.
// Workspace: masks 5x2MB | Wt 512KB

#define NPTS 65536
#define HDIM 256

typedef _Float16 half8_t __attribute__((ext_vector_type(8)));
typedef _Float16 half4_t __attribute__((ext_vector_type(4)));
typedef float floatx4 __attribute__((ext_vector_type(4)));

// ---------------------------------------------------------------- fused fp32 forward (np/BLAS-exact) — v11 verbatim
// 1024 threads = 16 waves, 128 pts/block. lane -> points (p0+lane, p0+64+lane);
// wave w -> cols c0=w*16 (W row slice wave-uniform -> s_load_dwordx16).
// hT[pt][k] stride 257 (odd -> conflict-free). Each output element is ONE
// sequential k-ascending fmaf chain from 0, bias added after (bit-exact vs np).
__global__ void __launch_bounds__(1024) fwd_fused_kernel(
    const float* __restrict__ x, const float* __restrict__ y, const float* __restrict__ t,
    const float* __restrict__ Win, const float* __restrict__ b_in,
    const float* __restrict__ Wh, const float* __restrict__ b_h,
    const float* __restrict__ Wout, const float* __restrict__ b_out,
    unsigned char* __restrict__ masks, float* __restrict__ out) {
  constexpr int SH = 257;              // odd stride: conflict-free b32
  __shared__ float hT[128 * SH];       // [pt][k]  131584 B
  __shared__ float pscr[16][132];      // wave partials for p (8448 B)

  const int tid = threadIdx.x;
  const int lane = tid & 63;
  const int w = __builtin_amdgcn_readfirstlane(tid >> 6);       // wave id 0..15
  const int c0 = w * 16;                                        // 16-col group
  const int p0 = blockIdx.x * 128;
  const int pA = p0 + lane;            // point A
  const int pB = p0 + 64 + lane;       // point B

  // ---- layer 1: dot = z @ Win (k ascending: x,y,t), then + b_in  [bit-exact]
  {
    float xa = x[pA], ya = y[pA], ta = t[pA];
    float xb = x[pB], yb = y[pB], tb = t[pB];
    unsigned ma = 0, mb = 0;
#pragma unroll
    for (int e = 0; e < 16; ++e) {
      int c = c0 + e;                  // uniform -> Win reads are scalar
      float w0 = Win[c], w1 = Win[256 + c], w2 = Win[512 + c], bb = b_in[c];
      float da = fmaf(xa, w0, 0.f);
      da = fmaf(ya, w1, da);
      da = fmaf(ta, w2, da);
      float aa = da + bb;
      bool posa = aa > 0.f;
      hT[lane * SH + c] = posa ? aa : 0.f;
      ma |= (posa ? 1u : 0u) << e;
      float db = fmaf(xb, w0, 0.f);
      db = fmaf(yb, w1, db);
      db = fmaf(tb, w2, db);
      float ab = db + bb;
      bool posb = ab > 0.f;
      hT[(64 + lane) * SH + c] = posb ? ab : 0.f;
      mb |= (posb ? 1u : 0u) << e;
    }
    *(unsigned short*)(masks + (size_t)pA * 32 + w * 2) = (unsigned short)ma;
    *(unsigned short*)(masks + (size_t)pB * 32 + w * 2) = (unsigned short)mb;
  }
  __syncthreads();

  // ---- hidden layers: single fp32 accumulator per element, k ascending, fmaf
  for (int l = 0; l < 4; ++l) {
    const float* Wl = Wh + (size_t)l * 65536 + c0;   // + uniform col offset
    float accA[16] = {};
    float accB[16] = {};
#pragma unroll 2
    for (int k = 0; k < 256; ++k) {
      float hA = hT[lane * SH + k];          // per-lane LDS, conflict-free
      float hB = hT[(64 + lane) * SH + k];
      const float* wr = Wl + k * 256;        // wave-uniform -> s_load_dwordx16
#pragma unroll
      for (int e = 0; e < 16; ++e) {
        float wv = wr[e];
        accA[e] = fmaf(hA, wv, accA[e]);
        accB[e] = fmaf(hB, wv, accB[e]);
      }
    }
    __syncthreads();                   // all hT reads done before overwrite
    unsigned ma = 0, mb = 0;
    float hnA[16], hnB[16];
#pragma unroll
    for (int e = 0; e < 16; ++e) {
      float bb = b_h[l * 256 + c0 + e];
      float aa = accA[e] + bb;
      bool posa = aa > 0.f;
      hnA[e] = posa ? aa : 0.f;
      ma |= (posa ? 1u : 0u) << e;
      float ab = accB[e] + bb;
      bool posb = ab > 0.f;
      hnB[e] = posb ? ab : 0.f;
      mb |= (posb ? 1u : 0u) << e;
    }
    *(unsigned short*)(masks + ((size_t)(l + 1) * NPTS + pA) * 32 + w * 2) =
        (unsigned short)ma;
    *(unsigned short*)(masks + ((size_t)(l + 1) * NPTS + pB) * 32 + w * 2) =
        (unsigned short)mb;
#pragma unroll
    for (int e = 0; e < 16; ++e) {
      hT[lane * SH + c0 + e] = hnA[e];
      hT[(64 + lane) * SH + c0 + e] = hnB[e];
    }
    __syncthreads();
  }

  // ---- p = h5 . Wout[:,1] + b_out[1]  (value output; order-insensitive at
  //      bf16 comparison granularity)
  {
    float sA = 0.f, sB = 0.f;
#pragma unroll
    for (int e = 0; e < 16; ++e) {
      float wv = Wout[2 * (c0 + e) + 1];
      sA = fmaf(hT[lane * SH + c0 + e], wv, sA);
      sB = fmaf(hT[(64 + lane) * SH + c0 + e], wv, sB);
    }
    pscr[w][lane] = sA;
    pscr[w][64 + lane] = sB;
  }
  __syncthreads();
  if (tid < 128) {
    float s2 = 0.f;
#pragma unroll
    for (int g = 0; g < 16; ++g) s2 += pscr[g][tid];
    out[2 * NPTS + p0 + tid] = s2 + b_out[1];
  }
}

// ---------------------------------------------------------------- prep: Wh fp32 [l][k][n] -> f16 [l][n][k]
__global__ void __launch_bounds__(256) prep_weights_kernel(
    const float* __restrict__ Wh, _Float16* __restrict__ Wt) {
  int i = blockIdx.x * 256 + threadIdx.x;   // 0..262143
  int l = i >> 16;
  int rem = i & 65535;
  int k = rem >> 8, n = rem & 255;
  Wt[(size_t)(l << 16) + n * 256 + k] = (_Float16)Wh[i];
}

// ---------------------------------------------------------------- fused tangent chain (init + 4 layers + finalize)
// Block: 256 thr = 4 waves. 32 points -> 64 rows (0..31 x-tangent, 32..63 y).
// Tile M=64 x N=256; wave wn owns 64 rows x 64 cols (acc 4x4 16x16 tiles).
// T lives in Apan (f16) across layers. v13: B fragments are loaded DIRECTLY
// from global Wt[n][k] into registers (per-lane b128; same values & MFMA
// order as the old Bpan path -> bit-identical). Only 2 barriers per layer.
// mfma_f32_16x16x32_f16: A[m=lane&15][k=quad*8+j], B[k=quad*8+j][n=lane&15],
//                        D[row=quad*4+reg][col=lane&15]  (verified layouts)
__global__ void __launch_bounds__(256, 4) tangent_fused_kernel(
    const float* __restrict__ Win,
    const _Float16* __restrict__ Wt,          // [l][n][k] (pre-transposed)
    const unsigned int* __restrict__ maskDw,  // [5][NPTS][8] dwords
    const float* __restrict__ Wout, float* __restrict__ out) {
  constexpr int SA = 264;   // A row stride (halves): 256 + 8 pad
  __shared__ alignas(16) _Float16 Apan[64 * SA];    // 33792 B
  __shared__ unsigned int smask[5 * 256];           // 5120 B

  const int tid = threadIdx.x;
  const int lane = tid & 63;
  const int wn = tid >> 6;          // wave = 64-col group
  const int l15 = lane & 15, quad = lane >> 4;
  const int p0 = blockIdx.x * 32;   // 32 points per block

  // ---- stage all 5 mask layers (32 pts x 8 dw each)
#pragma unroll
  for (int i = 0; i < 5; ++i)
    smask[i * 256 + tid] = maskDw[(size_t)i * NPTS * 8 + (size_t)p0 * 8 + tid];
  __syncthreads();

  // ---- init T1 into Apan: row<32 -> x-tangent (Win row 0), row>=32 -> y (row 1)
#pragma unroll
  for (int i = 0; i < 8; ++i) {
    int g = tid + 256 * i;          // 0..2047 col-groups of 8
    int row = g >> 5, cg = g & 31;
    int c0 = cg * 8, pt = row & 31, tg = row >> 5;
    unsigned dw = smask[pt * 8 + (c0 >> 5)];
    half8_t v;
#pragma unroll
    for (int e = 0; e < 8; ++e) {
      bool m = (dw >> ((cg & 3) * 8 + e)) & 1;
      v[e] = m ? (_Float16)Win[tg * 256 + c0 + e] : (_Float16)0.f;
    }
    *(half8_t*)&Apan[row * SA + c0] = v;
  }
  __syncthreads();

  // ---- 4 layers: acc = A @ W_l, gate by mask[l+1], back into Apan as f16
  for (int l = 0; l < 4; ++l) {
    // per-lane B base: row n = wn*64 + l15 (+ nj*16), k offset quad*8
    const _Float16* Bl =
        Wt + (size_t)l * 65536 + (size_t)(wn * 64 + l15) * 256 + quad * 8;
    floatx4 acc[4][4] = {};   // [mi][nj]
#pragma unroll
    for (int kp = 0; kp < 4; ++kp) {
#pragma unroll
      for (int ks = 0; ks < 2; ++ks) {
        half8_t af[4], bf[4];
#pragma unroll
        for (int nj = 0; nj < 4; ++nj)   // global b128, vmcnt-pipelined
          bf[nj] = *(const half8_t*)(Bl + nj * 16 * 256 + kp * 64 + ks * 32);
#pragma unroll
        for (int mi = 0; mi < 4; ++mi)
          af[mi] = *(const half8_t*)&Apan[(mi * 16 + l15) * SA + kp * 64 + ks * 32 + quad * 8];
#pragma unroll
        for (int mi = 0; mi < 4; ++mi)
#pragma unroll
          for (int nj = 0; nj < 4; ++nj)
            acc[mi][nj] = __builtin_amdgcn_mfma_f32_16x16x32_f16(af[mi], bf[nj], acc[mi][nj], 0, 0, 0);
      }
    }
    __syncthreads();          // all Apan reads of this layer done
    // gated write-back (C layout -> A storage), f16
    const unsigned int* ml = &smask[(l + 1) * 256];
#pragma unroll
    for (int mi = 0; mi < 4; ++mi) {
#pragma unroll
      for (int r = 0; r < 4; ++r) {
        int row = mi * 16 + quad * 4 + r;
        int pt = row & 31;
#pragma unroll
        for (int nj = 0; nj < 4; ++nj) {
          int C = wn * 64 + nj * 16 + l15;
          bool m = (ml[pt * 8 + (C >> 5)] >> (C & 31)) & 1;
          Apan[row * SA + C] = m ? (_Float16)acc[mi][nj][r] : (_Float16)0.f;
        }
      }
    }
    __syncthreads();
  }

  // ---- finalize from Apan (= T5 gated): per row, dots with Wout cols
  float4 wA = *(const float4*)(Wout + lane * 8);      // (W[c][0],W[c][1],W[c+1][0],W[c+1][1])
  float4 wB = *(const float4*)(Wout + lane * 8 + 4);
  float w0[4] = {wA.x, wA.z, wB.x, wB.z};  // Wout[:,0] for cols lane*4..+3
  float w1[4] = {wA.y, wA.w, wB.y, wB.w};  // Wout[:,1]
#pragma unroll
  for (int i = 0; i < 16; ++i) {
    int row = wn * 16 + i;
    half4_t hv = *(const half4_t*)&Apan[row * SA + lane * 4];
    float s0 = 0.f, s1 = 0.f;
#pragma unroll
    for (int e = 0; e < 4; ++e) {
      float fv = (float)hv[e];
      s0 = fmaf(fv, w0[e], s0);
      s1 = fmaf(fv, w1[e], s1);
    }
#pragma unroll
    for (int off = 1; off < 64; off <<= 1) {
      s0 += __shfl_xor(s0, off);
      s1 += __shfl_xor(s1, off);
    }
    if (lane == 0) {
      int pt = p0 + (row & 31);
      if (row < 32) {                 // x-tangent: v = -psi_x, f = p_x
        out[NPTS + pt] = -s0;
        out[3 * NPTS + pt] = s1;
      } else {                        // y-tangent: u = psi_y, g = p_y
        out[pt] = s0;
        out[4 * NPTS + pt] = s1;
      }
    }
  }
}

// ---------------------------------------------------------------- launch
extern "C" void kernel_launch(void* const* d_in, const int* in_sizes, int n_in,
                              void* d_out, int out_size, void* d_ws, size_t ws_size,
                              hipStream_t stream) {
  const float* x = (const float*)d_in[0];
  const float* y = (const float*)d_in[1];
  const float* t = (const float*)d_in[2];
  const float* Win = (const float*)d_in[3];
  const float* b_in = (const float*)d_in[4];
  const float* Wh = (const float*)d_in[5];
  const float* b_h = (const float*)d_in[6];
  const float* Wout = (const float*)d_in[7];
  const float* b_out = (const float*)d_in[8];
  float* out = (float*)d_out;

  char* ws = (char*)d_ws;
  constexpr size_t MASK_SZ = (size_t)NPTS * 32;       // 2 MB per layer
  unsigned char* masks = (unsigned char*)ws;
  _Float16* Wt = (_Float16*)(ws + 5 * MASK_SZ);

  // weight transpose/cast first (independent of fwd)
  prep_weights_kernel<<<1024, 256, 0, stream>>>(Wh, Wt);

  // fp32 np-exact forward: masks L0..L4 + p
  fwd_fused_kernel<<<NPTS / 128, 1024, 0, stream>>>(
      x, y, t, Win, b_in, Wh, b_h, Wout, b_out, masks, out);

  // fused tangent chain: init + 4 MFMA layers + finalize (u,v,f,g)
  tangent_fused_kernel<<<NPTS / 32, 256, 0, stream>>>(
      Win, Wt, (const unsigned int*)masks, Wout, out);
}

// Round 14
// 601.987 us; speedup vs baseline: 1.9471x; 1.0624x over previous
//
#include <hip/hip_runtime.h>
#include <hip/hip_bf16.h>

// N=65536 points, H=256, 4 hidden layers, ReLU MLP -> (psi,p).
// ReLU => piecewise linear => Hessians vanish; f = p_x, g = p_y (RHO=1).
// Pipeline:
//   1) fp32 forward replicating np/BLAS arithmetic BIT-EXACTLY
//      (k-ascending single-acc chain, bias after, mask = a>0).
//      v14: v11 mapping (1024 thr = 16 waves x 16 cols, 2 pts/lane,
//      hT[128][257], W via wave-uniform s_load) with the inner FMAs as
//      HAND-WRITTEN v_pk_fma_f32 (two independent col-chains per pack,
//      IEEE-identical per half -> masks bit-exact). Scalar-issue floor
//      219us halves to ~110; K$ supply (~4.3 B/cyc/CU) now binds (~204us).
//   2) fused tangent kernel, v7 version REVERTED (Bpan LDS staging;
//      v13's direct-global B was latency-bound and slower).
// Workspace: masks 5x2MB | Wt 512KB

#define NPTS 65536
#define HDIM 256

typedef _Float16 half8_t __attribute__((ext_vector_type(8)));
typedef _Float16 half4_t __attribute__((ext_vector_type(4)));
typedef float floatx4 __attribute__((ext_vector_type(4)));
typedef float float2v __attribute__((ext_vector_type(2)));

// ---------------------------------------------------------------- fused fp32 forward (np/BLAS-exact, packed fp32)
// 1024 threads = 16 waves, 128 pts/block. lane -> points (p0+lane, p0+64+lane);
// wave w -> cols c0=w*16 (W row slice wave-uniform -> s_load). Inner loop:
// 8 col-pairs x 2 pts as v_pk_fma_f32 (SGPR-pair W operand). hT[pt][k]
// stride 257 (conflict-free). Each output element is ONE sequential
// k-ascending fma chain from 0, bias added after (bit-exact vs np).
__global__ void __launch_bounds__(1024) fwd_fused_kernel(
    const float* __restrict__ x, const float* __restrict__ y, const float* __restrict__ t,
    const float* __restrict__ Win, const float* __restrict__ b_in,
    const float* __restrict__ Wh, const float* __restrict__ b_h,
    const float* __restrict__ Wout, const float* __restrict__ b_out,
    unsigned char* __restrict__ masks, float* __restrict__ out) {
  constexpr int SH = 257;              // odd stride: conflict-free b32
  __shared__ float hT[128 * SH];       // [pt][k]  131584 B
  __shared__ float pscr[16][132];      // wave partials for p (8448 B)

  const int tid = threadIdx.x;
  const int lane = tid & 63;
  const int w = __builtin_amdgcn_readfirstlane(tid >> 6);       // wave id 0..15
  const int c0 = w * 16;                                        // 16-col group
  const int p0 = blockIdx.x * 128;
  const int pA = p0 + lane;            // point A
  const int pB = p0 + 64 + lane;       // point B

  // ---- layer 1: dot = z @ Win (k ascending: x,y,t), then + b_in  [bit-exact]
  {
    float xa = x[pA], ya = y[pA], ta = t[pA];
    float xb = x[pB], yb = y[pB], tb = t[pB];
    unsigned ma = 0, mb = 0;
#pragma unroll
    for (int e = 0; e < 16; ++e) {
      int c = c0 + e;                  // uniform -> Win reads are scalar
      float w0 = Win[c], w1 = Win[256 + c], w2 = Win[512 + c], bb = b_in[c];
      float da = fmaf(xa, w0, 0.f);
      da = fmaf(ya, w1, da);
      da = fmaf(ta, w2, da);
      float aa = da + bb;
      bool posa = aa > 0.f;
      hT[lane * SH + c] = posa ? aa : 0.f;
      ma |= (posa ? 1u : 0u) << e;
      float db = fmaf(xb, w0, 0.f);
      db = fmaf(yb, w1, db);
      db = fmaf(tb, w2, db);
      float ab = db + bb;
      bool posb = ab > 0.f;
      hT[(64 + lane) * SH + c] = posb ? ab : 0.f;
      mb |= (posb ? 1u : 0u) << e;
    }
    *(unsigned short*)(masks + (size_t)pA * 32 + w * 2) = (unsigned short)ma;
    *(unsigned short*)(masks + (size_t)pB * 32 + w * 2) = (unsigned short)mb;
  }
  __syncthreads();

  // ---- hidden layers: packed fp32; each half of each pack is one sequential
  //      k-ascending IEEE fma chain (bit-exact vs np reference)
  for (int l = 0; l < 4; ++l) {
    const float* Wl = Wh + (size_t)l * 65536 + c0;   // + uniform col offset
    float2v accA[8] = {};              // col pairs (c0+2e, c0+2e+1), point A
    float2v accB[8] = {};              // point B
#pragma unroll 2
    for (int k = 0; k < 256; ++k) {
      float hA = hT[lane * SH + k];          // per-lane LDS, conflict-free
      float hB = hT[(64 + lane) * SH + k];
      float2v h2A = {hA, hA};
      float2v h2B = {hB, hB};
      const float* wr = Wl + k * 256;        // wave-uniform -> s_load
#pragma unroll
      for (int e = 0; e < 8; ++e) {
        float2v w2 = *(const float2v*)(wr + 2 * e);   // SGPR pair
        asm("v_pk_fma_f32 %0, %2, %3, %0\n\t"
            "v_pk_fma_f32 %1, %4, %3, %1"
            : "+v"(accA[e]), "+v"(accB[e])
            : "v"(h2A), "s"(w2), "v"(h2B));
      }
    }
    __syncthreads();                   // all hT reads done before overwrite
    unsigned ma = 0, mb = 0;
    float hnA[16], hnB[16];
#pragma unroll
    for (int e = 0; e < 16; ++e) {
      float bb = b_h[l * 256 + c0 + e];
      float aa = accA[e >> 1][e & 1] + bb;
      bool posa = aa > 0.f;
      hnA[e] = posa ? aa : 0.f;
      ma |= (posa ? 1u : 0u) << e;
      float ab = accB[e >> 1][e & 1] + bb;
      bool posb = ab > 0.f;
      hnB[e] = posb ? ab : 0.f;
      mb |= (posb ? 1u : 0u) << e;
    }
    *(unsigned short*)(masks + ((size_t)(l + 1) * NPTS + pA) * 32 + w * 2) =
        (unsigned short)ma;
    *(unsigned short*)(masks + ((size_t)(l + 1) * NPTS + pB) * 32 + w * 2) =
        (unsigned short)mb;
#pragma unroll
    for (int e = 0; e < 16; ++e) {
      hT[lane * SH + c0 + e] = hnA[e];
      hT[(64 + lane) * SH + c0 + e] = hnB[e];
    }
    __syncthreads();
  }

  // ---- p = h5 . Wout[:,1] + b_out[1]  (value output; order-insensitive at
  //      bf16 comparison granularity)
  {
    float sA = 0.f, sB = 0.f;
#pragma unroll
    for (int e = 0; e < 16; ++e) {
      float wv = Wout[2 * (c0 + e) + 1];
      sA = fmaf(hT[lane * SH + c0 + e], wv, sA);
      sB = fmaf(hT[(64 + lane) * SH + c0 + e], wv, sB);
    }
    pscr[w][lane] = sA;
    pscr[w][64 + lane] = sB;
  }
  __syncthreads();
  if (tid < 128) {
    float s2 = 0.f;
#pragma unroll
    for (int g = 0; g < 16; ++g) s2 += pscr[g][tid];
    out[2 * NPTS + p0 + tid] = s2 + b_out[1];
  }
}

// ---------------------------------------------------------------- prep: Wh fp32 [l][k][n] -> f16 [l][n][k]
__global__ void __launch_bounds__(256) prep_weights_kernel(
    const float* __restrict__ Wh, _Float16* __restrict__ Wt) {
  int i = blockIdx.x * 256 + threadIdx.x;   // 0..262143
  int l = i >> 16;
  int rem = i & 65535;
  int k = rem >> 8, n = rem & 255;
  Wt[(size_t)(l << 16) + n * 256 + k] = (_Float16)Wh[i];
}

// ---------------------------------------------------------------- fused tangent chain (init + 4 layers + finalize)
// v7 version (reverted from v13). Block: 256 thr = 4 waves. 32 points ->
// 64 rows (0..31 x-tangent, 32..63 y). Tile M=64 x N=256; wave wn owns
// 64 rows x 64 cols. T lives in Apan (f16); W streamed in 64-k chunks to Bpan.
// mfma_f32_16x16x32_f16: A[m=lane&15][k=quad*8+j], B[k=quad*8+j][n=lane&15],
//                        D[row=quad*4+reg][col=lane&15]  (verified layouts)
__global__ void __launch_bounds__(256, 2) tangent_fused_kernel(
    const float* __restrict__ Win,
    const _Float16* __restrict__ Wt,          // [l][n][k] (pre-transposed)
    const unsigned int* __restrict__ maskDw,  // [5][NPTS][8] dwords
    const float* __restrict__ Wout, float* __restrict__ out) {
  constexpr int SA = 264;   // A row stride (halves): 256 + 8 pad
  constexpr int SB = 72;    // B row stride (halves): 64 + 8 pad
  __shared__ alignas(16) _Float16 Apan[64 * SA];    // 33792 B
  __shared__ alignas(16) _Float16 Bpan[256 * SB];   // 36864 B
  __shared__ unsigned int smask[5 * 256];           // 5120 B

  const int tid = threadIdx.x;
  const int lane = tid & 63;
  const int wn = tid >> 6;          // wave = 64-col group
  const int l15 = lane & 15, quad = lane >> 4;
  const int p0 = blockIdx.x * 32;   // 32 points per block

  // ---- stage all 5 mask layers (32 pts x 8 dw each)
#pragma unroll
  for (int i = 0; i < 5; ++i)
    smask[i * 256 + tid] = maskDw[(size_t)i * NPTS * 8 + (size_t)p0 * 8 + tid];
  __syncthreads();

  // ---- init T1 into Apan: row<32 -> x-tangent (Win row 0), row>=32 -> y (row 1)
#pragma unroll
  for (int i = 0; i < 8; ++i) {
    int g = tid + 256 * i;          // 0..2047 col-groups of 8
    int row = g >> 5, cg = g & 31;
    int c0 = cg * 8, pt = row & 31, tg = row >> 5;
    unsigned dw = smask[pt * 8 + (c0 >> 5)];
    half8_t v;
#pragma unroll
    for (int e = 0; e < 8; ++e) {
      bool m = (dw >> ((cg & 3) * 8 + e)) & 1;
      v[e] = m ? (_Float16)Win[tg * 256 + c0 + e] : (_Float16)0.f;
    }
    *(half8_t*)&Apan[row * SA + c0] = v;
  }

  // ---- 4 layers: acc = A @ W_l, gate by mask[l+1], back into Apan as f16
  for (int l = 0; l < 4; ++l) {
    const _Float16* Wl = Wt + (size_t)l * 65536;
    floatx4 acc[4][4] = {};   // [mi][nj]
    for (int kp = 0; kp < 4; ++kp) {
      __syncthreads();        // Bpan free (and Apan init/writes visible)
      // stage B chunk: 256 n-rows x 64 k halves
#pragma unroll
      for (int i = 0; i < 8; ++i) {
        int g = tid + 256 * i;      // 0..2047 half8 segs
        int row = g >> 3, seg = g & 7;
        *(half8_t*)&Bpan[row * SB + seg * 8] =
            *(const half8_t*)(Wl + (size_t)row * 256 + kp * 64 + seg * 8);
      }
      __syncthreads();
#pragma unroll
      for (int ks = 0; ks < 2; ++ks) {
        half8_t af[4], bf[4];
#pragma unroll
        for (int mi = 0; mi < 4; ++mi)
          af[mi] = *(const half8_t*)&Apan[(mi * 16 + l15) * SA + kp * 64 + ks * 32 + quad * 8];
#pragma unroll
        for (int nj = 0; nj < 4; ++nj)
          bf[nj] = *(const half8_t*)&Bpan[(wn * 64 + nj * 16 + l15) * SB + ks * 32 + quad * 8];
#pragma unroll
        for (int mi = 0; mi < 4; ++mi)
#pragma unroll
          for (int nj = 0; nj < 4; ++nj)
            acc[mi][nj] = __builtin_amdgcn_mfma_f32_16x16x32_f16(af[mi], bf[nj], acc[mi][nj], 0, 0, 0);
      }
    }
    __syncthreads();          // all Apan reads of this layer done
    // gated write-back (C layout -> A storage), f16
    const unsigned int* ml = &smask[(l + 1) * 256];
#pragma unroll
    for (int mi = 0; mi < 4; ++mi) {
#pragma unroll
      for (int r = 0; r < 4; ++r) {
        int row = mi * 16 + quad * 4 + r;
        int pt = row & 31;
#pragma unroll
        for (int nj = 0; nj < 4; ++nj) {
          int C = wn * 64 + nj * 16 + l15;
          bool m = (ml[pt * 8 + (C >> 5)] >> (C & 31)) & 1;
          Apan[row * SA + C] = m ? (_Float16)acc[mi][nj][r] : (_Float16)0.f;
        }
      }
    }
    __syncthreads();
  }

  // ---- finalize from Apan (= T5 gated): per row, dots with Wout cols
  float4 wA = *(const float4*)(Wout + lane * 8);      // (W[c][0],W[c][1],W[c+1][0],W[c+1][1])
  float4 wB = *(const float4*)(Wout + lane * 8 + 4);
  float w0[4] = {wA.x, wA.z, wB.x, wB.z};  // Wout[:,0] for cols lane*4..+3
  float w1[4] = {wA.y, wA.w, wB.y, wB.w};  // Wout[:,1]
#pragma unroll
  for (int i = 0; i < 16; ++i) {
    int row = wn * 16 + i;
    half4_t hv = *(const half4_t*)&Apan[row * SA + lane * 4];
    float s0 = 0.f, s1 = 0.f;
#pragma unroll
    for (int e = 0; e < 4; ++e) {
      float fv = (float)hv[e];
      s0 = fmaf(fv, w0[e], s0);
      s1 = fmaf(fv, w1[e], s1);
    }
#pragma unroll
    for (int off = 1; off < 64; off <<= 1) {
      s0 += __shfl_xor(s0, off);
      s1 += __shfl_xor(s1, off);
    }
    if (lane == 0) {
      int pt = p0 + (row & 31);
      if (row < 32) {                 // x-tangent: v = -psi_x, f = p_x
        out[NPTS + pt] = -s0;
        out[3 * NPTS + pt] = s1;
      } else {                        // y-tangent: u = psi_y, g = p_y
        out[pt] = s0;
        out[4 * NPTS + pt] = s1;
      }
    }
  }
}

// ---------------------------------------------------------------- launch
extern "C" void kernel_launch(void* const* d_in, const int* in_sizes, int n_in,
                              void* d_out, int out_size, void* d_ws, size_t ws_size,
                              hipStream_t stream) {
  const float* x = (const float*)d_in[0];
  const float* y = (const float*)d_in[1];
  const float* t = (const float*)d_in[2];
  const float* Win = (const float*)d_in[3];
  const float* b_in = (const float*)d_in[4];
  const float* Wh = (const float*)d_in[5];
  const float* b_h = (const float*)d_in[6];
  const float* Wout = (const float*)d_in[7];
  const float* b_out = (const float*)d_in[8];
  float* out = (float*)d_out;

  char* ws = (char*)d_ws;
  constexpr size_t MASK_SZ = (size_t)NPTS * 32;       // 2 MB per layer
  unsigned char* masks = (unsigned char*)ws;
  _Float16* Wt = (_Float16*)(ws + 5 * MASK_SZ);

  // weight transpose/cast first (independent of fwd)
  prep_weights_kernel<<<1024, 256, 0, stream>>>(Wh, Wt);

  // fp32 np-exact forward (packed fp32): masks L0..L4 + p
  fwd_fused_kernel<<<NPTS / 128, 1024, 0, stream>>>(
      x, y, t, Win, b_in, Wh, b_h, Wout, b_out, masks, out);

  // fused tangent chain: init + 4 MFMA layers + finalize (u,v,f,g)
  tangent_fused_kernel<<<NPTS / 32, 256, 0, stream>>>(
      Win, Wt, (const unsigned int*)masks, Wout, out);
}

// Round 15
// 554.632 us; speedup vs baseline: 2.1133x; 1.0854x over previous
//
#include <hip/hip_runtime.h>
#include <hip/hip_bf16.h>

// N=65536 points, H=256, 4 hidden layers, ReLU MLP -> (psi,p).
// ReLU => piecewise linear => Hessians vanish; f = p_x, g = p_y (RHO=1).
// Pipeline:
//   1) fp32 forward replicating np/BLAS arithmetic BIT-EXACTLY (v11 kernel,
//      UNMODIFIED: 1024 thr = 16 waves x 16 cols, 2 pts/lane, hT[128][257],
//      W via wave-uniform s_load; ~404 us = ~83% of the scalar-FMA issue
//      ceiling; v12 VMEM-W and v14 packed-asm detours both regressed).
//   2) v15 fused tangent kernel: WAVE-PRIVATE B staging. Each wave bulk-
//      loads its own 64-row B slice into its own Bpan quarter (coalesced
//      b128) and reads it back with NO barriers (within-wave lgkmcnt
//      ordering). Barriers drop 34 -> 2 per layer. Same values, same MFMA
//      order -> bit-identical outputs to v7.
// Workspace: masks 5x2MB | Wt 512KB

#define NPTS 65536
#define HDIM 256

typedef _Float16 half8_t __attribute__((ext_vector_type(8)));
typedef _Float16 half4_t __attribute__((ext_vector_type(4)));
typedef float floatx4 __attribute__((ext_vector_type(4)));

// ---------------------------------------------------------------- fused fp32 forward (np/BLAS-exact) — v11 verbatim
// 1024 threads = 16 waves, 128 pts/block. lane -> points (p0+lane, p0+64+lane);
// wave w -> cols c0=w*16 (W row slice wave-uniform -> s_load_dwordx16).
// hT[pt][k] stride 257 (odd -> conflict-free). Each output element is ONE
// sequential k-ascending fmaf chain from 0, bias added after (bit-exact vs np).
__global__ void __launch_bounds__(1024) fwd_fused_kernel(
    const float* __restrict__ x, const float* __restrict__ y, const float* __restrict__ t,
    const float* __restrict__ Win, const float* __restrict__ b_in,
    const float* __restrict__ Wh, const float* __restrict__ b_h,
    const float* __restrict__ Wout, const float* __restrict__ b_out,
    unsigned char* __restrict__ masks, float* __restrict__ out) {
  constexpr int SH = 257;              // odd stride: conflict-free b32
  __shared__ float hT[128 * SH];       // [pt][k]  131584 B
  __shared__ float pscr[16][132];      // wave partials for p (8448 B)

  const int tid = threadIdx.x;
  const int lane = tid & 63;
  const int w = __builtin_amdgcn_readfirstlane(tid >> 6);       // wave id 0..15
  const int c0 = w * 16;                                        // 16-col group
  const int p0 = blockIdx.x * 128;
  const int pA = p0 + lane;            // point A
  const int pB = p0 + 64 + lane;       // point B

  // ---- layer 1: dot = z @ Win (k ascending: x,y,t), then + b_in  [bit-exact]
  {
    float xa = x[pA], ya = y[pA], ta = t[pA];
    float xb = x[pB], yb = y[pB], tb = t[pB];
    unsigned ma = 0, mb = 0;
#pragma unroll
    for (int e = 0; e < 16; ++e) {
      int c = c0 + e;                  // uniform -> Win reads are scalar
      float w0 = Win[c], w1 = Win[256 + c], w2 = Win[512 + c], bb = b_in[c];
      float da = fmaf(xa, w0, 0.f);
      da = fmaf(ya, w1, da);
      da = fmaf(ta, w2, da);
      float aa = da + bb;
      bool posa = aa > 0.f;
      hT[lane * SH + c] = posa ? aa : 0.f;
      ma |= (posa ? 1u : 0u) << e;
      float db = fmaf(xb, w0, 0.f);
      db = fmaf(yb, w1, db);
      db = fmaf(tb, w2, db);
      float ab = db + bb;
      bool posb = ab > 0.f;
      hT[(64 + lane) * SH + c] = posb ? ab : 0.f;
      mb |= (posb ? 1u : 0u) << e;
    }
    *(unsigned short*)(masks + (size_t)pA * 32 + w * 2) = (unsigned short)ma;
    *(unsigned short*)(masks + (size_t)pB * 32 + w * 2) = (unsigned short)mb;
  }
  __syncthreads();

  // ---- hidden layers: single fp32 accumulator per element, k ascending, fmaf
  for (int l = 0; l < 4; ++l) {
    const float* Wl = Wh + (size_t)l * 65536 + c0;   // + uniform col offset
    float accA[16] = {};
    float accB[16] = {};
#pragma unroll 2
    for (int k = 0; k < 256; ++k) {
      float hA = hT[lane * SH + k];          // per-lane LDS, conflict-free
      float hB = hT[(64 + lane) * SH + k];
      const float* wr = Wl + k * 256;        // wave-uniform -> s_load_dwordx16
#pragma unroll
      for (int e = 0; e < 16; ++e) {
        float wv = wr[e];
        accA[e] = fmaf(hA, wv, accA[e]);
        accB[e] = fmaf(hB, wv, accB[e]);
      }
    }
    __syncthreads();                   // all hT reads done before overwrite
    unsigned ma = 0, mb = 0;
    float hnA[16], hnB[16];
#pragma unroll
    for (int e = 0; e < 16; ++e) {
      float bb = b_h[l * 256 + c0 + e];
      float aa = accA[e] + bb;
      bool posa = aa > 0.f;
      hnA[e] = posa ? aa : 0.f;
      ma |= (posa ? 1u : 0u) << e;
      float ab = accB[e] + bb;
      bool posb = ab > 0.f;
      hnB[e] = posb ? ab : 0.f;
      mb |= (posb ? 1u : 0u) << e;
    }
    *(unsigned short*)(masks + ((size_t)(l + 1) * NPTS + pA) * 32 + w * 2) =
        (unsigned short)ma;
    *(unsigned short*)(masks + ((size_t)(l + 1) * NPTS + pB) * 32 + w * 2) =
        (unsigned short)mb;
#pragma unroll
    for (int e = 0; e < 16; ++e) {
      hT[lane * SH + c0 + e] = hnA[e];
      hT[(64 + lane) * SH + c0 + e] = hnB[e];
    }
    __syncthreads();
  }

  // ---- p = h5 . Wout[:,1] + b_out[1]  (value output; order-insensitive at
  //      bf16 comparison granularity)
  {
    float sA = 0.f, sB = 0.f;
#pragma unroll
    for (int e = 0; e < 16; ++e) {
      float wv = Wout[2 * (c0 + e) + 1];
      sA = fmaf(hT[lane * SH + c0 + e], wv, sA);
      sB = fmaf(hT[(64 + lane) * SH + c0 + e], wv, sB);
    }
    pscr[w][lane] = sA;
    pscr[w][64 + lane] = sB;
  }
  __syncthreads();
  if (tid < 128) {
    float s2 = 0.f;
#pragma unroll
    for (int g = 0; g < 16; ++g) s2 += pscr[g][tid];
    out[2 * NPTS + p0 + tid] = s2 + b_out[1];
  }
}

// ---------------------------------------------------------------- prep: Wh fp32 [l][k][n] -> f16 [l][n][k]
__global__ void __launch_bounds__(256) prep_weights_kernel(
    const float* __restrict__ Wh, _Float16* __restrict__ Wt) {
  int i = blockIdx.x * 256 + threadIdx.x;   // 0..262143
  int l = i >> 16;
  int rem = i & 65535;
  int k = rem >> 8, n = rem & 255;
  Wt[(size_t)(l << 16) + n * 256 + k] = (_Float16)Wh[i];
}

// ---------------------------------------------------------------- fused tangent chain (init + 4 layers + finalize)
// Block: 256 thr = 4 waves. 32 points -> 64 rows (0..31 x-tangent, 32..63 y).
// Tile M=64 x N=256; wave wn owns 64 rows x 64 cols (acc 4x4 16x16 tiles).
// T lives in Apan (f16) across layers. v15: B staged WAVE-PRIVATELY --
// wave wn loads its own 64 B-rows into Bpan[wn] (coalesced b128) and reads
// them back with no barrier (within-wave lgkmcnt ordering). Only the two
// Apan fences per layer remain as barriers.
// mfma_f32_16x16x32_f16: A[m=lane&15][k=quad*8+j], B[k=quad*8+j][n=lane&15],
//                        D[row=quad*4+reg][col=lane&15]  (verified layouts)
__global__ void __launch_bounds__(256, 2) tangent_fused_kernel(
    const float* __restrict__ Win,
    const _Float16* __restrict__ Wt,          // [l][n][k] (pre-transposed)
    const unsigned int* __restrict__ maskDw,  // [5][NPTS][8] dwords
    const float* __restrict__ Wout, float* __restrict__ out) {
  constexpr int SA = 264;   // A row stride (halves): 256 + 8 pad
  constexpr int SB = 72;    // B row stride (halves): 64 + 8 pad
  __shared__ alignas(16) _Float16 Apan[64 * SA];        // 33792 B
  __shared__ alignas(16) _Float16 Bpan[4][64 * SB];     // 4 x 9216 B = 36864 B
  __shared__ unsigned int smask[5 * 256];               // 5120 B

  const int tid = threadIdx.x;
  const int lane = tid & 63;
  const int wn = tid >> 6;          // wave = 64-col group
  const int l15 = lane & 15, quad = lane >> 4;
  const int p0 = blockIdx.x * 32;   // 32 points per block

  // ---- stage all 5 mask layers (32 pts x 8 dw each)
#pragma unroll
  for (int i = 0; i < 5; ++i)
    smask[i * 256 + tid] = maskDw[(size_t)i * NPTS * 8 + (size_t)p0 * 8 + tid];
  __syncthreads();

  // ---- init T1 into Apan: row<32 -> x-tangent (Win row 0), row>=32 -> y (row 1)
#pragma unroll
  for (int i = 0; i < 8; ++i) {
    int g = tid + 256 * i;          // 0..2047 col-groups of 8
    int row = g >> 5, cg = g & 31;
    int c0 = cg * 8, pt = row & 31, tg = row >> 5;
    unsigned dw = smask[pt * 8 + (c0 >> 5)];
    half8_t v;
#pragma unroll
    for (int e = 0; e < 8; ++e) {
      bool m = (dw >> ((cg & 3) * 8 + e)) & 1;
      v[e] = m ? (_Float16)Win[tg * 256 + c0 + e] : (_Float16)0.f;
    }
    *(half8_t*)&Apan[row * SA + c0] = v;
  }
  __syncthreads();                  // Apan init visible to all waves

  // ---- 4 layers: acc = A @ W_l, gate by mask[l+1], back into Apan as f16
  for (int l = 0; l < 4; ++l) {
    // wave-private B slice: rows wn*64 .. wn*64+63 of Wt layer l
    const _Float16* Bw = Wt + (size_t)l * 65536 + (size_t)(wn * 64) * 256;
    _Float16* Bp = &Bpan[wn][0];
    floatx4 acc[4][4] = {};   // [mi][nj]
#pragma unroll
    for (int kp = 0; kp < 4; ++kp) {
      // stage this wave's 64 B-rows x 64 k (8 KB), coalesced b128; no barrier:
      // within-wave LDS write->read ordering is enforced by lgkmcnt.
#pragma unroll
      for (int i = 0; i < 8; ++i) {
        int idx = lane + 64 * i;    // 0..511 half8 segs
        int row = idx >> 3, seg = idx & 7;
        *(half8_t*)&Bp[row * SB + seg * 8] =
            *(const half8_t*)(Bw + (size_t)row * 256 + kp * 64 + seg * 8);
      }
#pragma unroll
      for (int ks = 0; ks < 2; ++ks) {
        half8_t af[4], bf[4];
#pragma unroll
        for (int mi = 0; mi < 4; ++mi)
          af[mi] = *(const half8_t*)&Apan[(mi * 16 + l15) * SA + kp * 64 + ks * 32 + quad * 8];
#pragma unroll
        for (int nj = 0; nj < 4; ++nj)
          bf[nj] = *(const half8_t*)&Bp[(nj * 16 + l15) * SB + ks * 32 + quad * 8];
#pragma unroll
        for (int mi = 0; mi < 4; ++mi)
#pragma unroll
          for (int nj = 0; nj < 4; ++nj)
            acc[mi][nj] = __builtin_amdgcn_mfma_f32_16x16x32_f16(af[mi], bf[nj], acc[mi][nj], 0, 0, 0);
      }
    }
    __syncthreads();          // all Apan reads of this layer done
    // gated write-back (C layout -> A storage), f16
    const unsigned int* ml = &smask[(l + 1) * 256];
#pragma unroll
    for (int mi = 0; mi < 4; ++mi) {
#pragma unroll
      for (int r = 0; r < 4; ++r) {
        int row = mi * 16 + quad * 4 + r;
        int pt = row & 31;
#pragma unroll
        for (int nj = 0; nj < 4; ++nj) {
          int C = wn * 64 + nj * 16 + l15;
          bool m = (ml[pt * 8 + (C >> 5)] >> (C & 31)) & 1;
          Apan[row * SA + C] = m ? (_Float16)acc[mi][nj][r] : (_Float16)0.f;
        }
      }
    }
    __syncthreads();
  }

  // ---- finalize from Apan (= T5 gated): per row, dots with Wout cols
  float4 wA = *(const float4*)(Wout + lane * 8);      // (W[c][0],W[c][1],W[c+1][0],W[c+1][1])
  float4 wB = *(const float4*)(Wout + lane * 8 + 4);
  float w0[4] = {wA.x, wA.z, wB.x, wB.z};  // Wout[:,0] for cols lane*4..+3
  float w1[4] = {wA.y, wA.w, wB.y, wB.w};  // Wout[:,1]
#pragma unroll
  for (int i = 0; i < 16; ++i) {
    int row = wn * 16 + i;
    half4_t hv = *(const half4_t*)&Apan[row * SA + lane * 4];
    float s0 = 0.f, s1 = 0.f;
#pragma unroll
    for (int e = 0; e < 4; ++e) {
      float fv = (float)hv[e];
      s0 = fmaf(fv, w0[e], s0);
      s1 = fmaf(fv, w1[e], s1);
    }
#pragma unroll
    for (int off = 1; off < 64; off <<= 1) {
      s0 += __shfl_xor(s0, off);
      s1 += __shfl_xor(s1, off);
    }
    if (lane == 0) {
      int pt = p0 + (row & 31);
      if (row < 32) {                 // x-tangent: v = -psi_x, f = p_x
        out[NPTS + pt] = -s0;
        out[3 * NPTS + pt] = s1;
      } else {                        // y-tangent: u = psi_y, g = p_y
        out[pt] = s0;
        out[4 * NPTS + pt] = s1;
      }
    }
  }
}

// ---------------------------------------------------------------- launch
extern "C" void kernel_launch(void* const* d_in, const int* in_sizes, int n_in,
                              void* d_out, int out_size, void* d_ws, size_t ws_size,
                              hipStream_t stream) {
  const float* x = (const float*)d_in[0];
  const float* y = (const float*)d_in[1];
  const float* t = (const float*)d_in[2];
  const float* Win = (const float*)d_in[3];
  const float* b_in = (const float*)d_in[4];
  const float* Wh = (const float*)d_in[5];
  const float* b_h = (const float*)d_in[6];
  const float* Wout = (const float*)d_in[7];
  const float* b_out = (const float*)d_in[8];
  float* out = (float*)d_out;

  char* ws = (char*)d_ws;
  constexpr size_t MASK_SZ = (size_t)NPTS * 32;       // 2 MB per layer
  unsigned char* masks = (unsigned char*)ws;
  _Float16* Wt = (_Float16*)(ws + 5 * MASK_SZ);

  // weight transpose/cast first (independent of fwd)
  prep_weights_kernel<<<1024, 256, 0, stream>>>(Wh, Wt);

  // fp32 np-exact forward: masks L0..L4 + p
  fwd_fused_kernel<<<NPTS / 128, 1024, 0, stream>>>(
      x, y, t, Win, b_in, Wh, b_h, Wout, b_out, masks, out);

  // fused tangent chain: init + 4 MFMA layers + finalize (u,v,f,g)
  tangent_fused_kernel<<<NPTS / 32, 256, 0, stream>>>(
      Win, Wt, (const unsigned int*)masks, Wout, out);
}